// Round 16
// baseline (302.680 us; speedup 1.0000x reference)
//
#include <hip/hip_runtime.h>

// ---------------------------------------------------------------- types
typedef _Float16 f16;
typedef _Float16 f16x8 __attribute__((ext_vector_type(8)));
typedef _Float16 f16x4 __attribute__((ext_vector_type(4)));
typedef _Float16 f16x2 __attribute__((ext_vector_type(2)));
typedef float f32x4 __attribute__((ext_vector_type(4)));
typedef float f32x16 __attribute__((ext_vector_type(16)));
typedef unsigned int u32;

#define DEVI __device__ __forceinline__

DEVI f32x4 mfma16(f16x8 a, f16x8 b, f32x4 c) {
    return __builtin_amdgcn_mfma_f32_16x16x32_f16(a, b, c, 0, 0, 0);
}
DEVI f32x16 mfma32(f16x8 a, f16x8 b, f32x16 c) {
    return __builtin_amdgcn_mfma_f32_32x32x16_f16(a, b, c, 0, 0, 0);
}

DEVI void gload_lds16(const void* g, void* l) {
    __builtin_amdgcn_global_load_lds(
        (const __attribute__((address_space(1))) void*)g,
        (__attribute__((address_space(3))) void*)l,
        16, 0, 0);
}

DEVI float gelu_exact(float v) {
    return 0.5f * v * (1.0f + erff(v * 0.70710678118654752f));
}

// ---------------------------------------------------------------- prep kernels
__global__ void cast_f16_kernel(const float* __restrict__ in, f16* __restrict__ out, int n4) {
    int i = blockIdx.x * 256 + threadIdx.x;
    if (i >= n4) return;
    float4 v = ((const float4*)in)[i];
    f16x4 o = {(f16)v.x, (f16)v.y, (f16)v.z, (f16)v.w};
    ((f16x4*)out)[i] = o;
}

__global__ __launch_bounds__(256) void transpose_cast_kernel(
    const float* __restrict__ W, f16* __restrict__ Wt, int Kd, int Nd) {
    __shared__ float tile[32][33];
    const int n0 = blockIdx.x * 32, k0 = blockIdx.y * 32;
    const int tx = threadIdx.x & 31, ty = threadIdx.x >> 5;
#pragma unroll
    for (int i = ty; i < 32; i += 8)
        tile[i][tx] = W[(size_t)(k0 + i) * Nd + n0 + tx];
    __syncthreads();
#pragma unroll
    for (int i = ty; i < 32; i += 8)
        Wt[(size_t)(n0 + i) * Kd + k0 + tx] = (f16)tile[tx][i];
}

__global__ void rope_table_kernel(float2* __restrict__ cs) {
    int idx = blockIdx.x * 256 + threadIdx.x;
    int l = idx >> 5, i = idx & 31;
    float inv = expf(-((float)(2 * i) / 64.0f) * logf(10000.0f));
    float fr = (float)l * inv;
    float sn, cn;
    sincosf(fr, &sn, &cn);
    cs[idx] = make_float2(cn, sn);
}

enum { EPI_NONE = 0, EPI_GELU = 1 };

// ---------------------------------------------------------------- GEMM 128x128 (r12-proven baseline)
template <int EPI, typename OutT, int KSPLIT>
__global__ __launch_bounds__(256) void gemm_bt(
    const f16* __restrict__ A, const f16* __restrict__ Bt,
    const float* __restrict__ bias, OutT* __restrict__ C0, OutT* __restrict__ C1,
    int M, int N, int K) {
    constexpr int BM = 128, BN = 128, BK = 64;
    __shared__ f16 lds_a[BM * BK];
    __shared__ f16 lds_b[BN * BK];

    const int nbn = N / BN;
    const int tiles = (M / BM) * nbn;
    const int ks = (KSPLIT == 1) ? 0 : (blockIdx.x / tiles);
    const int rem = blockIdx.x - ks * tiles;
    const int bm = rem / nbn, bn = rem % nbn;
    const int tid = threadIdx.x;
    const int wave = tid >> 6, lane = tid & 63;
    const int ln = lane & 31, hi2 = lane >> 5;
    const int wr = (wave >> 1) * 64, wc = (wave & 1) * 64;

    const int Klen = K / KSPLIT;
    const int kbeg = ks * Klen;

    const f16* Ag = A + (size_t)bm * BM * K;
    const f16* Bg = Bt + (size_t)bn * BN * K;
    OutT* C = ks ? C1 : C0;

    f32x16 acc[2][2] = {};

    for (int k0 = kbeg; k0 < kbeg + Klen; k0 += BK) {
        __syncthreads();
#pragma unroll
        for (int c = 0; c < 4; ++c) {
            int pc = wave * 256 + c * 64 + lane;
            int r = pc >> 3;
            int col = ((pc & 7) ^ (r & 7)) * 8;
            gload_lds16(Ag + (size_t)r * K + k0 + col, &lds_a[(wave * 256 + c * 64) * 8]);
            gload_lds16(Bg + (size_t)r * K + k0 + col, &lds_b[(wave * 256 + c * 64) * 8]);
        }
        __syncthreads();
#pragma unroll
        for (int ks16 = 0; ks16 < 4; ++ks16) {
            const int slot = (ks16 * 2 + hi2) ^ (ln & 7);
            f16x8 af[2], bf[2];
#pragma unroll
            for (int mi = 0; mi < 2; ++mi)
                af[mi] = *(const f16x8*)&lds_a[(wr + mi * 32 + ln) * 64 + slot * 8];
#pragma unroll
            for (int nj = 0; nj < 2; ++nj)
                bf[nj] = *(const f16x8*)&lds_b[(wc + nj * 32 + ln) * 64 + slot * 8];
#pragma unroll
            for (int mi = 0; mi < 2; ++mi)
#pragma unroll
                for (int nj = 0; nj < 2; ++nj)
                    acc[mi][nj] = mfma32(af[mi], bf[nj], acc[mi][nj]);
        }
    }
#pragma unroll
    for (int mi = 0; mi < 2; ++mi)
#pragma unroll
        for (int nj = 0; nj < 2; ++nj) {
            const int col = bn * BN + wc + nj * 32 + ln;
            const float bv = (KSPLIT == 1 || ks == 0) ? bias[col] : 0.0f;
#pragma unroll
            for (int r = 0; r < 16; ++r) {
                const int row = bm * BM + wr + mi * 32 + (r & 3) + 8 * (r >> 2) + 4 * hi2;
                float v = acc[mi][nj][r] + bv;
                if (EPI == EPI_GELU) v = gelu_exact(v);
                C[(size_t)row * N + col] = (OutT)v;
            }
        }
}

// ---------------------------------------------------------------- GEMM 256x256, 8 waves, counted-vmcnt pipeline
// (r10-proven correct; used ONLY for grids with >= 1 block/CU, i.e. ffn1.)
// Schedule per K-tile (4 quadrant phases):
//   ph0: reads(A0,B0)  stage A1(k+1)   vmcnt(6)
//   ph1: reads(A0,B1)  stage B1(k+1)
//   ph2: reads(A1,B0)  stage A0(k+2)
//   ph3: reads(A1,B1)  stage B0(k+2)   vmcnt(8)
template <int EPI, typename OutT, int KSPLIT>
__global__ __launch_bounds__(512, 2) void gemm8(
    const f16* __restrict__ A, const f16* __restrict__ Bt,
    const float* __restrict__ bias,
    OutT* __restrict__ C0, OutT* __restrict__ C1,
    OutT* __restrict__ C2, OutT* __restrict__ C3,
    int M, int N, int K) {
    extern __shared__ f16 lds[];           // 65536 f16 = 128 KiB

    const int nbn = N >> 8;
    const int tiles = (M >> 8) * nbn;
    int bid = blockIdx.x;
    bid = (bid & 7) * (gridDim.x >> 3) + (bid >> 3);   // XCD swizzle (grid % 8 == 0)
    const int ks = (KSPLIT == 1) ? 0 : bid / tiles;
    const int rem = bid - ks * tiles;
    const int bm = rem / nbn, bn = rem % nbn;

    const int wave = threadIdx.x >> 6, lane = threadIdx.x & 63;
    const int lo = lane & 15, hi = lane >> 4;
    const int wqm = wave >> 2, wqn = wave & 3;          // quadrant sub-tile 64x32

    const int Klen = K / KSPLIT;
    const int kbeg = ks * Klen;
    const int niter = Klen >> 6;

    const f16* Ag = A + (size_t)(bm << 8) * K;
    const f16* Bg = Bt + (size_t)(bn << 8) * K;
    OutT* C = (KSPLIT == 1 || ks == 0) ? C0 : (ks == 1 ? C1 : (ks == 2 ? C2 : C3));

    const int s_row0 = (wave << 3) + (lane >> 3);
    const int s_col = ((lane & 7) << 3) ^ (((lane >> 5) & 1) << 4);

    auto stage_half = [&](int mat, int half, int par_t, int kb) {
        const f16* G = mat ? Bg : Ag;
        const int dstb = mat * 32768 + half * 16384 + par_t * 8192 + (wave << 9);
        gload_lds16(G + (size_t)(half * 128 + s_row0) * K + kb + s_col, &lds[dstb]);
        gload_lds16(G + (size_t)(half * 128 + s_row0 + 64) * K + kb + s_col, &lds[dstb + 4096]);
    };

    f32x4 acc[4][4][2] = {};

    stage_half(0, 0, 0, kbeg);
    stage_half(1, 0, 0, kbeg);
    stage_half(0, 1, 0, kbeg);
    stage_half(1, 1, 0, kbeg);
    if (niter > 1) {
        stage_half(0, 0, 1, kbeg + 64);
        stage_half(1, 0, 1, kbeg + 64);
        asm volatile("s_waitcnt vmcnt(4)" ::: "memory");
    } else {
        asm volatile("s_waitcnt vmcnt(0)" ::: "memory");
    }
    __builtin_amdgcn_s_barrier();

    for (int it = 0; it < niter; ++it) {
        const int par = (it & 1) << 13;
        const bool tail = (it >= niter - 2);
        const int kb1 = kbeg + (it + 1) * 64;
        const int kb2 = kbeg + (it + 2) * 64;

#pragma unroll
        for (int p = 0; p < 4; ++p) {
            const int mh = p >> 1, nh = p & 1;
            f16x8 af[4][2], bf[2][2];
#pragma unroll
            for (int i = 0; i < 4; ++i) {
                const int arow = wqm * 64 + i * 16 + lo;
                const int sw = ((arow >> 2) & 1) << 4;
#pragma unroll
                for (int kk = 0; kk < 2; ++kk)
                    af[i][kk] = *(const f16x8*)&lds[mh * 16384 + par + arow * 64 + ((kk * 32 + hi * 8) ^ sw)];
            }
#pragma unroll
            for (int j = 0; j < 2; ++j) {
                const int brow = wqn * 32 + j * 16 + lo;
                const int sw = ((brow >> 2) & 1) << 4;
#pragma unroll
                for (int kk = 0; kk < 2; ++kk)
                    bf[j][kk] = *(const f16x8*)&lds[32768 + nh * 16384 + par + brow * 64 + ((kk * 32 + hi * 8) ^ sw)];
            }
            if (p == 0 && it + 1 < niter) stage_half(0, 1, (it + 1) & 1, kb1);
            if (p == 1 && it + 1 < niter) stage_half(1, 1, (it + 1) & 1, kb1);
            if (p == 2 && it + 2 < niter) stage_half(0, 0, it & 1, kb2);
            if (p == 3 && it + 2 < niter) stage_half(1, 0, it & 1, kb2);
            if (p == 0) {
                if (tail) asm volatile("s_waitcnt vmcnt(0)" ::: "memory");
                else      asm volatile("s_waitcnt vmcnt(6)" ::: "memory");
            }
            if (p == 3) {
                if (tail) asm volatile("s_waitcnt vmcnt(0)" ::: "memory");
                else      asm volatile("s_waitcnt vmcnt(8)" ::: "memory");
            }
            __builtin_amdgcn_s_barrier();
            asm volatile("s_waitcnt lgkmcnt(0)" ::: "memory");
            __builtin_amdgcn_s_setprio(1);
#pragma unroll
            for (int i = 0; i < 4; ++i)
#pragma unroll
                for (int j = 0; j < 2; ++j)
#pragma unroll
                    for (int kk = 0; kk < 2; ++kk)
                        acc[p][i][j] = mfma16(af[i][kk], bf[j][kk], acc[p][i][j]);
            __builtin_amdgcn_s_setprio(0);
            __builtin_amdgcn_s_barrier();
        }
    }

#pragma unroll
    for (int q = 0; q < 4; ++q) {
        const int mh = q >> 1, nh = q & 1;
#pragma unroll
        for (int i = 0; i < 4; ++i)
#pragma unroll
            for (int j = 0; j < 2; ++j) {
                const int col = (bn << 8) + nh * 128 + wqn * 32 + j * 16 + lo;
                const float bv = (KSPLIT == 1 || ks == 0) ? bias[col] : 0.0f;
#pragma unroll
                for (int r = 0; r < 4; ++r) {
                    const int row = (bm << 8) + mh * 128 + wqm * 64 + i * 16 + hi * 4 + r;
                    float v = acc[q][i][j][r] + bv;
                    if (EPI == EPI_GELU) v = gelu_exact(v);
                    C[(size_t)row * N + col] = (OutT)v;
                }
            }
    }
}

// ---------------------------------------------------------------- RoPE + pack (fragment-packed K/V)
// Kp rows PERMUTED (key-bits 2<->3) so QK^T's D-layout feeds PV directly.
__global__ __launch_bounds__(256) void rope_pack_kernel(
    const f16* __restrict__ qkv, const float2* __restrict__ cs,
    f16* __restrict__ Q, f16* __restrict__ Kp, f16* __restrict__ Vp) {
    constexpr int L = 2048;
    constexpr float QSC = 0.125f * 1.4426950408889634f;
    const int blk = blockIdx.x;             // B*H*(L/64) = 1024
    const int lt = blk & 31, h = (blk >> 5) & 15, b = blk >> 9;
    const int t = threadIdx.x, r = t >> 2, sub = t & 3;
    const int l = lt * 64 + r;
    const size_t base = (size_t)(b * L + l) * 3072 + h * 64 + sub * 8;

    f16x8 qlo = *(const f16x8*)&qkv[base];
    f16x8 qhi = *(const f16x8*)&qkv[base + 32];
    f16x8 klo = *(const f16x8*)&qkv[base + 1024];
    f16x8 khi = *(const f16x8*)&qkv[base + 1024 + 32];
    f16x8 vlo = *(const f16x8*)&qkv[base + 2048];
    f16x8 vhi = *(const f16x8*)&qkv[base + 2048 + 32];

    f16x8 qol, qoh, kol, koh;
#pragma unroll
    for (int j = 0; j < 8; ++j) {
        float2 c = cs[l * 32 + sub * 8 + j];
        float q1 = (float)qlo[j], q2 = (float)qhi[j];
        float k1 = (float)klo[j], k2 = (float)khi[j];
        qol[j] = (f16)((q1 * c.x - q2 * c.y) * QSC);
        qoh[j] = (f16)((q2 * c.x + q1 * c.y) * QSC);
        kol[j] = (f16)(k1 * c.x - k2 * c.y);
        koh[j] = (f16)(k2 * c.x + k1 * c.y);
    }
    const size_t qbase = (size_t)((b * 16 + h) * L + l) * 64 + sub * 8;
    *(f16x8*)&Q[qbase] = qol;
    *(f16x8*)&Q[qbase + 32] = qoh;

    {
        const int kb = l >> 5, kn = l & 31;
        const int kr = (kn & ~12) | ((kn & 4) << 1) | ((kn & 8) >> 1);
        const size_t kbase = ((size_t)(b * 16 + h) * 64 + kb) * 4;
        const int lane_off = ((sub & 1) * 32 + kr) * 8;
        *(f16x8*)&Kp[(kbase + (sub >> 1)) * 512 + lane_off] = kol;
        *(f16x8*)&Kp[(kbase + 2 + (sub >> 1)) * 512 + lane_off] = koh;
    }

    __shared__ f16 vt[64][80];
#pragma unroll
    for (int j = 0; j < 8; ++j) {
        vt[sub * 8 + j][r] = vlo[j];
        vt[sub * 8 + 32 + j][r] = vhi[j];
    }
    __syncthreads();
    {
        const int c32 = t >> 7, f = (t >> 5) & 3, ln = t & 31;
        const int d = (f >> 1) * 32 + ln;
        const size_t vbase = (((size_t)(b * 16 + h) * 64 + lt * 2 + c32) * 4 + f) * 512;
        const int colb = c32 * 32 + (f & 1) * 16;
#pragma unroll
        for (int hi2 = 0; hi2 < 2; ++hi2)
            *(f16x8*)&Vp[vbase + (hi2 * 32 + ln) * 8] =
                *(const f16x8*)&vt[d][colb + hi2 * 8];
    }
}

// ---------------------------------------------------------------- attention (split-K=4 flash, packed K/V)
__global__ __launch_bounds__(256) void attn_fwd(
    const f16* __restrict__ Q, const f16* __restrict__ Kp,
    const f16* __restrict__ Vp, f16* __restrict__ Out) {
    constexpr int L = 2048, HD = 64;
    const int bh = blockIdx.x >> 6;
    const int qt = blockIdx.x & 63;
    const int wave = threadIdx.x >> 6, lane = threadIdx.x & 63;
    const int ln = lane & 31, hi2 = lane >> 5;
    const int q0 = qt * 32;
    const int kb_beg = wave * 16;

    const f16* Qh = Q + (size_t)bh * L * HD;
    const f16* Kh = Kp + (size_t)bh * 64 * 4 * 512;
    const f16* Vh = Vp + (size_t)bh * 64 * 4 * 512;

    f16x8 bq[4];
#pragma unroll
    for (int dblk = 0; dblk < 4; ++dblk)
        bq[dblk] = *(const f16x8*)&Qh[(size_t)(q0 + ln) * HD + dblk * 16 + hi2 * 8];

    const f16 one = (f16)1.0f;
    const f16x8 ones = {one, one, one, one, one, one, one, one};

    f32x16 oacc0 = {}, oacc1 = {}, sacc = {};

    f16x8 ak[4];
#pragma unroll
    for (int dblk = 0; dblk < 4; ++dblk)
        ak[dblk] = *(const f16x8*)&Kh[(size_t)(kb_beg * 4 + dblk) * 512 + lane * 8];

    for (int step = 0; step < 16; ++step) {
        const int kb = kb_beg + step;
        f32x16 st = {};
#pragma unroll
        for (int dblk = 0; dblk < 4; ++dblk)
            st = mfma32(ak[dblk], bq[dblk], st);

        const f16* vblk = &Vh[(size_t)kb * 4 * 512];
        f16x8 av0 = *(const f16x8*)&vblk[0 * 512 + lane * 8];
        f16x8 av1 = *(const f16x8*)&vblk[1 * 512 + lane * 8];
        f16x8 av2 = *(const f16x8*)&vblk[2 * 512 + lane * 8];
        f16x8 av3 = *(const f16x8*)&vblk[3 * 512 + lane * 8];
        if (step < 15) {
            const f16* kblk = &Kh[(size_t)(kb + 1) * 4 * 512];
#pragma unroll
            for (int dblk = 0; dblk < 4; ++dblk)
                ak[dblk] = *(const f16x8*)&kblk[dblk * 512 + lane * 8];
        }

        float p[16];
#pragma unroll
        for (int r = 0; r < 16; ++r) p[r] = exp2f(st[r]);
        union U8 { u32 w[4]; f16x8 v; };
        U8 ub0, ub1;
#pragma unroll
        for (int i = 0; i < 4; ++i) {
            ub0.w[i] = __builtin_bit_cast(u32, __builtin_amdgcn_cvt_pkrtz(p[2 * i], p[2 * i + 1]));
            ub1.w[i] = __builtin_bit_cast(u32, __builtin_amdgcn_cvt_pkrtz(p[8 + 2 * i], p[9 + 2 * i]));
        }

        oacc0 = mfma32(av0, ub0.v, oacc0);
        oacc1 = mfma32(av2, ub0.v, oacc1);
        sacc  = mfma32(ones, ub0.v, sacc);
        oacc0 = mfma32(av1, ub1.v, oacc0);
        oacc1 = mfma32(av3, ub1.v, oacc1);
        sacc  = mfma32(ones, ub1.v, sacc);
    }

    const float l_run = sacc[0];

    __shared__ f16 obuf[2][32][80];
    __shared__ float sarr[4][32];
    const float s_self = __log2f(l_run);
    const float rl = 1.0f / l_run;

    if (wave & 1) {
        const int slot = wave >> 1;
#pragma unroll
        for (int r = 0; r < 16; ++r) {
            int d = (r & 3) + 8 * (r >> 2) + 4 * hi2;
            obuf[slot][ln][d] = (f16)(oacc0[r] * rl);
            obuf[slot][ln][32 + d] = (f16)(oacc1[r] * rl);
        }
        if (!hi2) sarr[wave][ln] = s_self;
    }
    __syncthreads();

    float om[32];
    float s01 = 0.0f;
    if (!(wave & 1)) {
        const int slot = wave >> 1;
        const float s_p = sarr[wave + 1][ln];
        const float e = exp2f(s_p - s_self);
        const float w_s = 1.0f / (1.0f + e);
        const float w_p = 1.0f - w_s;
        s01 = s_self + __log2f(1.0f + e);
#pragma unroll
        for (int r = 0; r < 16; ++r) {
            int d = (r & 3) + 8 * (r >> 2) + 4 * hi2;
            om[r]      = oacc0[r] * rl * w_s + (float)obuf[slot][ln][d] * w_p;
            om[16 + r] = oacc1[r] * rl * w_s + (float)obuf[slot][ln][32 + d] * w_p;
        }
    }
    __syncthreads();
    if (wave == 2) {
#pragma unroll
        for (int r = 0; r < 16; ++r) {
            int d = (r & 3) + 8 * (r >> 2) + 4 * hi2;
            obuf[1][ln][d] = (f16)om[r];
            obuf[1][ln][32 + d] = (f16)om[16 + r];
        }
        if (!hi2) sarr[2][ln] = s01;
    }
    __syncthreads();
    if (wave == 0) {
        const float s23 = sarr[2][ln];
        const float e = exp2f(s23 - s01);
        const float w0 = 1.0f / (1.0f + e);
        const float w1 = 1.0f - w0;
#pragma unroll
        for (int r = 0; r < 16; ++r) {
            int d = (r & 3) + 8 * (r >> 2) + 4 * hi2;
            obuf[0][ln][d] = (f16)(om[r] * w0 + (float)obuf[1][ln][d] * w1);
            obuf[0][ln][32 + d] = (f16)(om[16 + r] * w0 + (float)obuf[1][ln][32 + d] * w1);
        }
    }
    __syncthreads();

    const int t = threadIdx.x;
    const int q = t >> 3, dseg = t & 7;
    const int b = bh >> 4, h = bh & 15;
    f16x8 o = *(const f16x8*)&obuf[0][q][dseg * 8];
    *(f16x8*)&Out[((size_t)(b * L + q0 + q) * 16 + h) * 64 + dseg * 8] = o;
}

// ---------------------------------------------------------------- residual + LayerNorm (sums NY partials)
template <bool WB, int NY>
__global__ __launch_bounds__(256) void ln_fused(
    const float* __restrict__ X, const float* __restrict__ Y0, const float* __restrict__ Y1,
    const float* __restrict__ g, const float* __restrict__ b,
    float* __restrict__ outF, f16* __restrict__ outH) {
    const int row = blockIdx.x, t = threadIdx.x;
    const float4 xv = ((const float4*)(X + (size_t)row * 1024))[t];
    const float4 yv = ((const float4*)(Y0 + (size_t)row * 1024))[t];
    float v0 = xv.x + yv.x, v1 = xv.y + yv.y, v2 = xv.z + yv.z, v3 = xv.w + yv.w;
    if constexpr (NY == 2) {
        const float4 zv = ((const float4*)(Y1 + (size_t)row * 1024))[t];
        v0 += zv.x; v1 += zv.y; v2 += zv.z; v3 += zv.w;
    }
    __shared__ float red[8];
    float s = v0 + v1 + v2 + v3;
#pragma unroll
    for (int m = 1; m < 64; m <<= 1) s += __shfl_xor(s, m);
    if ((t & 63) == 0) red[t >> 6] = s;
    __syncthreads();
    float mu = (red[0] + red[1] + red[2] + red[3]) * (1.0f / 1024.0f);
    float d0 = v0 - mu, d1 = v1 - mu, d2 = v2 - mu, d3 = v3 - mu;
    float q = d0 * d0 + d1 * d1 + d2 * d2 + d3 * d3;
#pragma unroll
    for (int m = 1; m < 64; m <<= 1) q += __shfl_xor(q, m);
    if ((t & 63) == 0) red[4 + (t >> 6)] = q;
    __syncthreads();
    float var = (red[4] + red[5] + red[6] + red[7]) * (1.0f / 1024.0f);
    float rs = rsqrtf(var + 1e-5f);
    const float4 gv = ((const float4*)g)[t];
    const float4 bv = ((const float4*)b)[t];
    float o0 = d0 * rs * gv.x + bv.x;
    float o1 = d1 * rs * gv.y + bv.y;
    float o2 = d2 * rs * gv.z + bv.z;
    float o3 = d3 * rs * gv.w + bv.w;
    float4 ov = {o0, o1, o2, o3};
    ((float4*)(outF + (size_t)row * 1024))[t] = ov;
    if constexpr (WB) {
        f16x4 oh = {(f16)o0, (f16)o1, (f16)o2, (f16)o3};
        ((f16x4*)(outH + (size_t)row * 1024))[t] = oh;
    }
}

// ---------------------------------------------------------------- launch
extern "C" void kernel_launch(void* const* d_in, const int* in_sizes, int n_in,
                              void* d_out, int out_size, void* d_ws, size_t ws_size,
                              hipStream_t stream) {
    const float* x      = (const float*)d_in[0];
    const float* qkv_w  = (const float*)d_in[1];
    const float* qkv_b  = (const float*)d_in[2];
    const float* out_w  = (const float*)d_in[3];
    const float* out_b  = (const float*)d_in[4];
    const float* ln1_g  = (const float*)d_in[5];
    const float* ln1_b  = (const float*)d_in[6];
    const float* ln2_g  = (const float*)d_in[7];
    const float* ln2_b  = (const float*)d_in[8];
    const float* ffn1_w = (const float*)d_in[9];
    const float* ffn1_b = (const float*)d_in[10];
    const float* ffn2_w = (const float*)d_in[11];
    const float* ffn2_b = (const float*)d_in[12];
    float* out = (float*)d_out;
    char* ws = (char*)d_ws;

    constexpr size_t SZ_XB      = 4096ull * 1024 * 2;
    constexpr size_t SZ_QKV_WT  = 3072ull * 1024 * 2;
    constexpr size_t SZ_OUT_WT  = 1024ull * 1024 * 2;
    constexpr size_t SZ_FFN1_WT = 4096ull * 1024 * 2;
    constexpr size_t SZ_FFN2_WT = 1024ull * 4096 * 2;
    constexpr size_t SZ_CS      = 2048ull * 32 * 8;
    constexpr size_t SZ_X1F     = 4096ull * 1024 * 4;
    constexpr size_t SZ_X1H     = 4096ull * 1024 * 2;
    constexpr size_t SZ_FFN2O   = 4096ull * 1024 * 4;
    constexpr size_t SZ_QH      = 32ull * 2048 * 64 * 2;   // 8 MB
    constexpr size_t SZ_REGB    = 4 * SZ_QH;
    constexpr size_t SZ_REGC    = 4096ull * 3072 * 2;

    size_t o = 0;
    auto take = [&](size_t sz) { size_t p = o; o += (sz + 255) & ~(size_t)255; return p; };
    const size_t O_XB      = take(SZ_XB);
    const size_t O_QKV_WT  = take(SZ_QKV_WT);
    const size_t O_OUT_WT  = take(SZ_OUT_WT);
    const size_t O_FFN1_WT = take(SZ_FFN1_WT);
    const size_t O_FFN2_WT = take(SZ_FFN2_WT);
    const size_t O_CS      = take(SZ_CS);
    const size_t O_X1F     = take(SZ_X1F);
    const size_t O_X1H     = take(SZ_X1H);
    const size_t O_FFN2O   = take(SZ_FFN2O);
    const size_t O_REGB    = take(SZ_REGB);
    const size_t O_REGC    = take(SZ_REGC);

    f16*    xb      = (f16*)(ws + O_XB);
    f16*    qkv_wt  = (f16*)(ws + O_QKV_WT);
    f16*    out_wt  = (f16*)(ws + O_OUT_WT);
    f16*    ffn1_wt = (f16*)(ws + O_FFN1_WT);
    f16*    ffn2_wt = (f16*)(ws + O_FFN2_WT);
    float2* cs      = (float2*)(ws + O_CS);
    float*  x1f     = (float*)(ws + O_X1F);
    f16*    x1h     = (f16*)(ws + O_X1H);
    float*  ffn2o   = (float*)(ws + O_FFN2O);
    f16*    Qb      = (f16*)(ws + O_REGB);
    f16*    Kpb     = (f16*)(ws + O_REGB + SZ_QH);
    f16*    Vpb     = (f16*)(ws + O_REGB + 2 * SZ_QH);
    f16*    attn_o  = (f16*)(ws + O_REGB + 3 * SZ_QH);
    f16*    hbuf    = (f16*)(ws + O_REGB);          // ffn1 out, after ln1
    float*  proj1   = (float*)(ws + O_REGB);        // 16MB, Q/Kp dead after attn
    f16*    qkvo    = (f16*)(ws + O_REGC);
    float*  proj0   = (float*)(ws + O_REGC);
    float*  f2p1    = (float*)(ws + O_REGC);        // proj0 dead by ffn2

    // allow 128 KiB dynamic LDS for the 8-phase GEMM (ffn1 only)
    (void)hipFuncSetAttribute((const void*)&gemm8<EPI_GELU, f16, 1>,
                              hipFuncAttributeMaxDynamicSharedMemorySize, 131072);

    cast_f16_kernel<<<4096, 256, 0, stream>>>(x, xb, 4096 * 1024 / 4);
    transpose_cast_kernel<<<dim3(96, 32), 256, 0, stream>>>(qkv_w, qkv_wt, 1024, 3072);
    transpose_cast_kernel<<<dim3(32, 32), 256, 0, stream>>>(out_w, out_wt, 1024, 1024);
    transpose_cast_kernel<<<dim3(128, 32), 256, 0, stream>>>(ffn1_w, ffn1_wt, 1024, 4096);
    transpose_cast_kernel<<<dim3(32, 128), 256, 0, stream>>>(ffn2_w, ffn2_wt, 4096, 1024);
    rope_table_kernel<<<256, 256, 0, stream>>>(cs);

    gemm_bt<EPI_NONE, f16, 1><<<32 * 24, 256, 0, stream>>>(
        xb, qkv_wt, qkv_b, qkvo, nullptr, 4096, 3072, 1024);
    rope_pack_kernel<<<1024, 256, 0, stream>>>(qkvo, cs, Qb, Kpb, Vpb);
    attn_fwd<<<2048, 256, 0, stream>>>(Qb, Kpb, Vpb, attn_o);
    gemm_bt<EPI_NONE, float, 2><<<32 * 8 * 2, 256, 0, stream>>>(
        attn_o, out_wt, out_b, proj0, proj1, 4096, 1024, 1024);
    ln_fused<true, 2><<<4096, 256, 0, stream>>>(x, proj0, proj1, ln1_g, ln1_b, x1f, x1h);
    gemm8<EPI_GELU, f16, 1><<<256, 512, 131072, stream>>>(
        x1h, ffn1_wt, ffn1_b, hbuf, nullptr, nullptr, nullptr, 4096, 4096, 1024);
    gemm_bt<EPI_NONE, float, 2><<<32 * 8 * 2, 256, 0, stream>>>(
        hbuf, ffn2_wt, ffn2_b, ffn2o, f2p1, 4096, 1024, 4096);
    ln_fused<false, 2><<<4096, 256, 0, stream>>>(x1f, ffn2o, f2p1, ln2_g, ln2_b, out, nullptr);
}

// Round 17
// 295.026 us; speedup vs baseline: 1.0259x; 1.0259x over previous
//
#include <hip/hip_runtime.h>

// ---------------------------------------------------------------- types
typedef _Float16 f16;
typedef _Float16 f16x8 __attribute__((ext_vector_type(8)));
typedef _Float16 f16x4 __attribute__((ext_vector_type(4)));
typedef _Float16 f16x2 __attribute__((ext_vector_type(2)));
typedef float f32x4 __attribute__((ext_vector_type(4)));
typedef float f32x16 __attribute__((ext_vector_type(16)));
typedef unsigned int u32;

#define DEVI __device__ __forceinline__

DEVI f32x4 mfma16(f16x8 a, f16x8 b, f32x4 c) {
    return __builtin_amdgcn_mfma_f32_16x16x32_f16(a, b, c, 0, 0, 0);
}
DEVI f32x16 mfma32(f16x8 a, f16x8 b, f32x16 c) {
    return __builtin_amdgcn_mfma_f32_32x32x16_f16(a, b, c, 0, 0, 0);
}

DEVI void gload_lds16(const void* g, void* l) {
    __builtin_amdgcn_global_load_lds(
        (const __attribute__((address_space(1))) void*)g,
        (__attribute__((address_space(3))) void*)l,
        16, 0, 0);
}

DEVI float gelu_exact(float v) {
    return 0.5f * v * (1.0f + erff(v * 0.70710678118654752f));
}

// ---------------------------------------------------------------- prep kernels
__global__ void cast_f16_kernel(const float* __restrict__ in, f16* __restrict__ out, int n4) {
    int i = blockIdx.x * 256 + threadIdx.x;
    if (i >= n4) return;
    float4 v = ((const float4*)in)[i];
    f16x4 o = {(f16)v.x, (f16)v.y, (f16)v.z, (f16)v.w};
    ((f16x4*)out)[i] = o;
}

__global__ __launch_bounds__(256) void transpose_cast_kernel(
    const float* __restrict__ W, f16* __restrict__ Wt, int Kd, int Nd) {
    __shared__ float tile[32][33];
    const int n0 = blockIdx.x * 32, k0 = blockIdx.y * 32;
    const int tx = threadIdx.x & 31, ty = threadIdx.x >> 5;
#pragma unroll
    for (int i = ty; i < 32; i += 8)
        tile[i][tx] = W[(size_t)(k0 + i) * Nd + n0 + tx];
    __syncthreads();
#pragma unroll
    for (int i = ty; i < 32; i += 8)
        Wt[(size_t)(n0 + i) * Kd + k0 + tx] = (f16)tile[tx][i];
}

__global__ void rope_table_kernel(float2* __restrict__ cs) {
    int idx = blockIdx.x * 256 + threadIdx.x;
    int l = idx >> 5, i = idx & 31;
    float inv = expf(-((float)(2 * i) / 64.0f) * logf(10000.0f));
    float fr = (float)l * inv;
    float sn, cn;
    sincosf(fr, &sn, &cn);
    cs[idx] = make_float2(cn, sn);
}

enum { EPI_NONE = 0, EPI_GELU = 1 };

// ---------------------------------------------------------------- GEMM 128x128 (r12-proven baseline)
template <int EPI, typename OutT, int KSPLIT>
__global__ __launch_bounds__(256) void gemm_bt(
    const f16* __restrict__ A, const f16* __restrict__ Bt,
    const float* __restrict__ bias, OutT* __restrict__ C0, OutT* __restrict__ C1,
    int M, int N, int K) {
    constexpr int BM = 128, BN = 128, BK = 64;
    __shared__ f16 lds_a[BM * BK];
    __shared__ f16 lds_b[BN * BK];

    const int nbn = N / BN;
    const int tiles = (M / BM) * nbn;
    const int ks = (KSPLIT == 1) ? 0 : (blockIdx.x / tiles);
    const int rem = blockIdx.x - ks * tiles;
    const int bm = rem / nbn, bn = rem % nbn;
    const int tid = threadIdx.x;
    const int wave = tid >> 6, lane = tid & 63;
    const int ln = lane & 31, hi2 = lane >> 5;
    const int wr = (wave >> 1) * 64, wc = (wave & 1) * 64;

    const int Klen = K / KSPLIT;
    const int kbeg = ks * Klen;

    const f16* Ag = A + (size_t)bm * BM * K;
    const f16* Bg = Bt + (size_t)bn * BN * K;
    OutT* C = ks ? C1 : C0;

    f32x16 acc[2][2] = {};

    for (int k0 = kbeg; k0 < kbeg + Klen; k0 += BK) {
        __syncthreads();
#pragma unroll
        for (int c = 0; c < 4; ++c) {
            int pc = wave * 256 + c * 64 + lane;
            int r = pc >> 3;
            int col = ((pc & 7) ^ (r & 7)) * 8;
            gload_lds16(Ag + (size_t)r * K + k0 + col, &lds_a[(wave * 256 + c * 64) * 8]);
            gload_lds16(Bg + (size_t)r * K + k0 + col, &lds_b[(wave * 256 + c * 64) * 8]);
        }
        __syncthreads();
#pragma unroll
        for (int ks16 = 0; ks16 < 4; ++ks16) {
            const int slot = (ks16 * 2 + hi2) ^ (ln & 7);
            f16x8 af[2], bf[2];
#pragma unroll
            for (int mi = 0; mi < 2; ++mi)
                af[mi] = *(const f16x8*)&lds_a[(wr + mi * 32 + ln) * 64 + slot * 8];
#pragma unroll
            for (int nj = 0; nj < 2; ++nj)
                bf[nj] = *(const f16x8*)&lds_b[(wc + nj * 32 + ln) * 64 + slot * 8];
#pragma unroll
            for (int mi = 0; mi < 2; ++mi)
#pragma unroll
                for (int nj = 0; nj < 2; ++nj)
                    acc[mi][nj] = mfma32(af[mi], bf[nj], acc[mi][nj]);
        }
    }
#pragma unroll
    for (int mi = 0; mi < 2; ++mi)
#pragma unroll
        for (int nj = 0; nj < 2; ++nj) {
            const int col = bn * BN + wc + nj * 32 + ln;
            const float bv = (KSPLIT == 1 || ks == 0) ? bias[col] : 0.0f;
#pragma unroll
            for (int r = 0; r < 16; ++r) {
                const int row = bm * BM + wr + mi * 32 + (r & 3) + 8 * (r >> 2) + 4 * hi2;
                float v = acc[mi][nj][r] + bv;
                if (EPI == EPI_GELU) v = gelu_exact(v);
                C[(size_t)row * N + col] = (OutT)v;
            }
        }
}

// ---------------------------------------------------------------- GEMM 256x256, 8 waves, counted-vmcnt pipeline
// FIXED swizzle (r16 lesson): full 3-bit XOR col8 ^= row&7 (all 32 banks),
// both-sides consistent: stage source col = ((lane&7)^(lane>>3))*8, read col
// = (c8 ^ (row&7))*8. Schedule per K-tile (4 quadrant phases):
//   ph0: reads(A0,B0)  stage A1(k+1)   vmcnt(6)
//   ph1: reads(A0,B1)  stage B1(k+1)
//   ph2: reads(A1,B0)  stage A0(k+2)
//   ph3: reads(A1,B1)  stage B0(k+2)   vmcnt(8)
template <int EPI, typename OutT, int KSPLIT>
__global__ __launch_bounds__(512, 2) void gemm8(
    const f16* __restrict__ A, const f16* __restrict__ Bt,
    const float* __restrict__ bias,
    OutT* __restrict__ C0, OutT* __restrict__ C1,
    OutT* __restrict__ C2, OutT* __restrict__ C3,
    int M, int N, int K) {
    extern __shared__ f16 lds[];           // 65536 f16 = 128 KiB

    const int nbn = N >> 8;
    const int tiles = (M >> 8) * nbn;
    int bid = blockIdx.x;
    bid = (bid & 7) * (gridDim.x >> 3) + (bid >> 3);   // XCD swizzle (grid % 8 == 0)
    const int ks = (KSPLIT == 1) ? 0 : bid / tiles;
    const int rem = bid - ks * tiles;
    const int bm = rem / nbn, bn = rem % nbn;

    const int wave = threadIdx.x >> 6, lane = threadIdx.x & 63;
    const int lo = lane & 15, hi = lane >> 4;
    const int wqm = wave >> 2, wqn = wave & 3;          // quadrant sub-tile 64x32

    const int Klen = K / KSPLIT;
    const int kbeg = ks * Klen;
    const int niter = Klen >> 6;

    const f16* Ag = A + (size_t)(bm << 8) * K;
    const f16* Bg = Bt + (size_t)(bn << 8) * K;
    OutT* C = (KSPLIT == 1 || ks == 0) ? C0 : (ks == 1 ? C1 : (ks == 2 ? C2 : C3));

    // staging: half-tile 128x64 f16 = 16 chunks of 1KB; chunk pc row-base pc*8,
    // lane covers (row = pc*8 + lane>>3, col8_phys = lane&7) which stores
    // logical col8 = (lane&7) ^ (row&7) = (lane&7) ^ (lane>>3).
    const int s_row0 = (wave << 3) + (lane >> 3);
    const int s_col = (((lane & 7) ^ (lane >> 3)) << 3);

    auto stage_half = [&](int mat, int half, int par_t, int kb) {
        const f16* G = mat ? Bg : Ag;
        const int dstb = mat * 32768 + half * 16384 + par_t * 8192 + (wave << 9);
        gload_lds16(G + (size_t)(half * 128 + s_row0) * K + kb + s_col, &lds[dstb]);
        gload_lds16(G + (size_t)(half * 128 + s_row0 + 64) * K + kb + s_col, &lds[dstb + 4096]);
    };

    f32x4 acc[4][4][2] = {};

    stage_half(0, 0, 0, kbeg);
    stage_half(1, 0, 0, kbeg);
    stage_half(0, 1, 0, kbeg);
    stage_half(1, 1, 0, kbeg);
    if (niter > 1) {
        stage_half(0, 0, 1, kbeg + 64);
        stage_half(1, 0, 1, kbeg + 64);
        asm volatile("s_waitcnt vmcnt(4)" ::: "memory");
    } else {
        asm volatile("s_waitcnt vmcnt(0)" ::: "memory");
    }
    __builtin_amdgcn_s_barrier();

    for (int it = 0; it < niter; ++it) {
        const int par = (it & 1) << 13;
        const bool tail = (it >= niter - 2);
        const int kb1 = kbeg + (it + 1) * 64;
        const int kb2 = kbeg + (it + 2) * 64;

#pragma unroll
        for (int p = 0; p < 4; ++p) {
            const int mh = p >> 1, nh = p & 1;
            f16x8 af[4][2], bf[2][2];
#pragma unroll
            for (int i = 0; i < 4; ++i) {
                const int arow = wqm * 64 + i * 16 + lo;
#pragma unroll
                for (int kk = 0; kk < 2; ++kk)
                    af[i][kk] = *(const f16x8*)&lds[mh * 16384 + par + arow * 64 + (((kk * 4 + hi) ^ (arow & 7)) << 3)];
            }
#pragma unroll
            for (int j = 0; j < 2; ++j) {
                const int brow = wqn * 32 + j * 16 + lo;
#pragma unroll
                for (int kk = 0; kk < 2; ++kk)
                    bf[j][kk] = *(const f16x8*)&lds[32768 + nh * 16384 + par + brow * 64 + (((kk * 4 + hi) ^ (brow & 7)) << 3)];
            }
            if (p == 0 && it + 1 < niter) stage_half(0, 1, (it + 1) & 1, kb1);
            if (p == 1 && it + 1 < niter) stage_half(1, 1, (it + 1) & 1, kb1);
            if (p == 2 && it + 2 < niter) stage_half(0, 0, it & 1, kb2);
            if (p == 3 && it + 2 < niter) stage_half(1, 0, it & 1, kb2);
            if (p == 0) {
                if (tail) asm volatile("s_waitcnt vmcnt(0)" ::: "memory");
                else      asm volatile("s_waitcnt vmcnt(6)" ::: "memory");
            }
            if (p == 3) {
                if (tail) asm volatile("s_waitcnt vmcnt(0)" ::: "memory");
                else      asm volatile("s_waitcnt vmcnt(8)" ::: "memory");
            }
            __builtin_amdgcn_s_barrier();
            asm volatile("s_waitcnt lgkmcnt(0)" ::: "memory");
            __builtin_amdgcn_s_setprio(1);
#pragma unroll
            for (int i = 0; i < 4; ++i)
#pragma unroll
                for (int j = 0; j < 2; ++j)
#pragma unroll
                    for (int kk = 0; kk < 2; ++kk)
                        acc[p][i][j] = mfma16(af[i][kk], bf[j][kk], acc[p][i][j]);
            __builtin_amdgcn_s_setprio(0);
            __builtin_amdgcn_s_barrier();
        }
    }

#pragma unroll
    for (int q = 0; q < 4; ++q) {
        const int mh = q >> 1, nh = q & 1;
#pragma unroll
        for (int i = 0; i < 4; ++i)
#pragma unroll
            for (int j = 0; j < 2; ++j) {
                const int col = (bn << 8) + nh * 128 + wqn * 32 + j * 16 + lo;
                const float bv = (KSPLIT == 1 || ks == 0) ? bias[col] : 0.0f;
#pragma unroll
                for (int r = 0; r < 4; ++r) {
                    const int row = (bm << 8) + mh * 128 + wqm * 64 + i * 16 + hi * 4 + r;
                    float v = acc[q][i][j][r] + bv;
                    if (EPI == EPI_GELU) v = gelu_exact(v);
                    C[(size_t)row * N + col] = (OutT)v;
                }
            }
    }
}

// ---------------------------------------------------------------- RoPE + pack (fragment-packed K/V)
// Kp rows PERMUTED (key-bits 2<->3) so QK^T's D-layout feeds PV directly.
__global__ __launch_bounds__(256) void rope_pack_kernel(
    const f16* __restrict__ qkv, const float2* __restrict__ cs,
    f16* __restrict__ Q, f16* __restrict__ Kp, f16* __restrict__ Vp) {
    constexpr int L = 2048;
    constexpr float QSC = 0.125f * 1.4426950408889634f;
    const int blk = blockIdx.x;             // B*H*(L/64) = 1024
    const int lt = blk & 31, h = (blk >> 5) & 15, b = blk >> 9;
    const int t = threadIdx.x, r = t >> 2, sub = t & 3;
    const int l = lt * 64 + r;
    const size_t base = (size_t)(b * L + l) * 3072 + h * 64 + sub * 8;

    f16x8 qlo = *(const f16x8*)&qkv[base];
    f16x8 qhi = *(const f16x8*)&qkv[base + 32];
    f16x8 klo = *(const f16x8*)&qkv[base + 1024];
    f16x8 khi = *(const f16x8*)&qkv[base + 1024 + 32];
    f16x8 vlo = *(const f16x8*)&qkv[base + 2048];
    f16x8 vhi = *(const f16x8*)&qkv[base + 2048 + 32];

    f16x8 qol, qoh, kol, koh;
#pragma unroll
    for (int j = 0; j < 8; ++j) {
        float2 c = cs[l * 32 + sub * 8 + j];
        float q1 = (float)qlo[j], q2 = (float)qhi[j];
        float k1 = (float)klo[j], k2 = (float)khi[j];
        qol[j] = (f16)((q1 * c.x - q2 * c.y) * QSC);
        qoh[j] = (f16)((q2 * c.x + q1 * c.y) * QSC);
        kol[j] = (f16)(k1 * c.x - k2 * c.y);
        koh[j] = (f16)(k2 * c.x + k1 * c.y);
    }
    const size_t qbase = (size_t)((b * 16 + h) * L + l) * 64 + sub * 8;
    *(f16x8*)&Q[qbase] = qol;
    *(f16x8*)&Q[qbase + 32] = qoh;

    {
        const int kb = l >> 5, kn = l & 31;
        const int kr = (kn & ~12) | ((kn & 4) << 1) | ((kn & 8) >> 1);
        const size_t kbase = ((size_t)(b * 16 + h) * 64 + kb) * 4;
        const int lane_off = ((sub & 1) * 32 + kr) * 8;
        *(f16x8*)&Kp[(kbase + (sub >> 1)) * 512 + lane_off] = kol;
        *(f16x8*)&Kp[(kbase + 2 + (sub >> 1)) * 512 + lane_off] = koh;
    }

    __shared__ f16 vt[64][80];
#pragma unroll
    for (int j = 0; j < 8; ++j) {
        vt[sub * 8 + j][r] = vlo[j];
        vt[sub * 8 + 32 + j][r] = vhi[j];
    }
    __syncthreads();
    {
        const int c32 = t >> 7, f = (t >> 5) & 3, ln = t & 31;
        const int d = (f >> 1) * 32 + ln;
        const size_t vbase = (((size_t)(b * 16 + h) * 64 + lt * 2 + c32) * 4 + f) * 512;
        const int colb = c32 * 32 + (f & 1) * 16;
#pragma unroll
        for (int hi2 = 0; hi2 < 2; ++hi2)
            *(f16x8*)&Vp[vbase + (hi2 * 32 + ln) * 8] =
                *(const f16x8*)&vt[d][colb + hi2 * 8];
    }
}

// ---------------------------------------------------------------- attention (split-K=4 flash, packed K/V)
__global__ __launch_bounds__(256) void attn_fwd(
    const f16* __restrict__ Q, const f16* __restrict__ Kp,
    const f16* __restrict__ Vp, f16* __restrict__ Out) {
    constexpr int L = 2048, HD = 64;
    const int bh = blockIdx.x >> 6;
    const int qt = blockIdx.x & 63;
    const int wave = threadIdx.x >> 6, lane = threadIdx.x & 63;
    const int ln = lane & 31, hi2 = lane >> 5;
    const int q0 = qt * 32;
    const int kb_beg = wave * 16;

    const f16* Qh = Q + (size_t)bh * L * HD;
    const f16* Kh = Kp + (size_t)bh * 64 * 4 * 512;
    const f16* Vh = Vp + (size_t)bh * 64 * 4 * 512;

    f16x8 bq[4];
#pragma unroll
    for (int dblk = 0; dblk < 4; ++dblk)
        bq[dblk] = *(const f16x8*)&Qh[(size_t)(q0 + ln) * HD + dblk * 16 + hi2 * 8];

    const f16 one = (f16)1.0f;
    const f16x8 ones = {one, one, one, one, one, one, one, one};

    f32x16 oacc0 = {}, oacc1 = {}, sacc = {};

    f16x8 ak[4];
#pragma unroll
    for (int dblk = 0; dblk < 4; ++dblk)
        ak[dblk] = *(const f16x8*)&Kh[(size_t)(kb_beg * 4 + dblk) * 512 + lane * 8];

    for (int step = 0; step < 16; ++step) {
        const int kb = kb_beg + step;
        f32x16 st = {};
#pragma unroll
        for (int dblk = 0; dblk < 4; ++dblk)
            st = mfma32(ak[dblk], bq[dblk], st);

        const f16* vblk = &Vh[(size_t)kb * 4 * 512];
        f16x8 av0 = *(const f16x8*)&vblk[0 * 512 + lane * 8];
        f16x8 av1 = *(const f16x8*)&vblk[1 * 512 + lane * 8];
        f16x8 av2 = *(const f16x8*)&vblk[2 * 512 + lane * 8];
        f16x8 av3 = *(const f16x8*)&vblk[3 * 512 + lane * 8];
        if (step < 15) {
            const f16* kblk = &Kh[(size_t)(kb + 1) * 4 * 512];
#pragma unroll
            for (int dblk = 0; dblk < 4; ++dblk)
                ak[dblk] = *(const f16x8*)&kblk[dblk * 512 + lane * 8];
        }

        float p[16];
#pragma unroll
        for (int r = 0; r < 16; ++r) p[r] = exp2f(st[r]);
        union U8 { u32 w[4]; f16x8 v; };
        U8 ub0, ub1;
#pragma unroll
        for (int i = 0; i < 4; ++i) {
            ub0.w[i] = __builtin_bit_cast(u32, __builtin_amdgcn_cvt_pkrtz(p[2 * i], p[2 * i + 1]));
            ub1.w[i] = __builtin_bit_cast(u32, __builtin_amdgcn_cvt_pkrtz(p[8 + 2 * i], p[9 + 2 * i]));
        }

        oacc0 = mfma32(av0, ub0.v, oacc0);
        oacc1 = mfma32(av2, ub0.v, oacc1);
        sacc  = mfma32(ones, ub0.v, sacc);
        oacc0 = mfma32(av1, ub1.v, oacc0);
        oacc1 = mfma32(av3, ub1.v, oacc1);
        sacc  = mfma32(ones, ub1.v, sacc);
    }

    const float l_run = sacc[0];

    __shared__ f16 obuf[2][32][80];
    __shared__ float sarr[4][32];
    const float s_self = __log2f(l_run);
    const float rl = 1.0f / l_run;

    if (wave & 1) {
        const int slot = wave >> 1;
#pragma unroll
        for (int r = 0; r < 16; ++r) {
            int d = (r & 3) + 8 * (r >> 2) + 4 * hi2;
            obuf[slot][ln][d] = (f16)(oacc0[r] * rl);
            obuf[slot][ln][32 + d] = (f16)(oacc1[r] * rl);
        }
        if (!hi2) sarr[wave][ln] = s_self;
    }
    __syncthreads();

    float om[32];
    float s01 = 0.0f;
    if (!(wave & 1)) {
        const int slot = wave >> 1;
        const float s_p = sarr[wave + 1][ln];
        const float e = exp2f(s_p - s_self);
        const float w_s = 1.0f / (1.0f + e);
        const float w_p = 1.0f - w_s;
        s01 = s_self + __log2f(1.0f + e);
#pragma unroll
        for (int r = 0; r < 16; ++r) {
            int d = (r & 3) + 8 * (r >> 2) + 4 * hi2;
            om[r]      = oacc0[r] * rl * w_s + (float)obuf[slot][ln][d] * w_p;
            om[16 + r] = oacc1[r] * rl * w_s + (float)obuf[slot][ln][32 + d] * w_p;
        }
    }
    __syncthreads();
    if (wave == 2) {
#pragma unroll
        for (int r = 0; r < 16; ++r) {
            int d = (r & 3) + 8 * (r >> 2) + 4 * hi2;
            obuf[1][ln][d] = (f16)om[r];
            obuf[1][ln][32 + d] = (f16)om[16 + r];
        }
        if (!hi2) sarr[2][ln] = s01;
    }
    __syncthreads();
    if (wave == 0) {
        const float s23 = sarr[2][ln];
        const float e = exp2f(s23 - s01);
        const float w0 = 1.0f / (1.0f + e);
        const float w1 = 1.0f - w0;
#pragma unroll
        for (int r = 0; r < 16; ++r) {
            int d = (r & 3) + 8 * (r >> 2) + 4 * hi2;
            obuf[0][ln][d] = (f16)(om[r] * w0 + (float)obuf[1][ln][d] * w1);
            obuf[0][ln][32 + d] = (f16)(om[16 + r] * w0 + (float)obuf[1][ln][32 + d] * w1);
        }
    }
    __syncthreads();

    const int t = threadIdx.x;
    const int q = t >> 3, dseg = t & 7;
    const int b = bh >> 4, h = bh & 15;
    f16x8 o = *(const f16x8*)&obuf[0][q][dseg * 8];
    *(f16x8*)&Out[((size_t)(b * L + q0 + q) * 16 + h) * 64 + dseg * 8] = o;
}

// ---------------------------------------------------------------- residual + LayerNorm (sums NY partials)
template <bool WB, int NY>
__global__ __launch_bounds__(256) void ln_fused(
    const float* __restrict__ X, const float* __restrict__ Y0, const float* __restrict__ Y1,
    const float* __restrict__ g, const float* __restrict__ b,
    float* __restrict__ outF, f16* __restrict__ outH) {
    const int row = blockIdx.x, t = threadIdx.x;
    const float4 xv = ((const float4*)(X + (size_t)row * 1024))[t];
    const float4 yv = ((const float4*)(Y0 + (size_t)row * 1024))[t];
    float v0 = xv.x + yv.x, v1 = xv.y + yv.y, v2 = xv.z + yv.z, v3 = xv.w + yv.w;
    if constexpr (NY == 2) {
        const float4 zv = ((const float4*)(Y1 + (size_t)row * 1024))[t];
        v0 += zv.x; v1 += zv.y; v2 += zv.z; v3 += zv.w;
    }
    __shared__ float red[8];
    float s = v0 + v1 + v2 + v3;
#pragma unroll
    for (int m = 1; m < 64; m <<= 1) s += __shfl_xor(s, m);
    if ((t & 63) == 0) red[t >> 6] = s;
    __syncthreads();
    float mu = (red[0] + red[1] + red[2] + red[3]) * (1.0f / 1024.0f);
    float d0 = v0 - mu, d1 = v1 - mu, d2 = v2 - mu, d3 = v3 - mu;
    float q = d0 * d0 + d1 * d1 + d2 * d2 + d3 * d3;
#pragma unroll
    for (int m = 1; m < 64; m <<= 1) q += __shfl_xor(q, m);
    if ((t & 63) == 0) red[4 + (t >> 6)] = q;
    __syncthreads();
    float var = (red[4] + red[5] + red[6] + red[7]) * (1.0f / 1024.0f);
    float rs = rsqrtf(var + 1e-5f);
    const float4 gv = ((const float4*)g)[t];
    const float4 bv = ((const float4*)b)[t];
    float o0 = d0 * rs * gv.x + bv.x;
    float o1 = d1 * rs * gv.y + bv.y;
    float o2 = d2 * rs * gv.z + bv.z;
    float o3 = d3 * rs * gv.w + bv.w;
    float4 ov = {o0, o1, o2, o3};
    ((float4*)(outF + (size_t)row * 1024))[t] = ov;
    if constexpr (WB) {
        f16x4 oh = {(f16)o0, (f16)o1, (f16)o2, (f16)o3};
        ((f16x4*)(outH + (size_t)row * 1024))[t] = oh;
    }
}

// ---------------------------------------------------------------- launch
extern "C" void kernel_launch(void* const* d_in, const int* in_sizes, int n_in,
                              void* d_out, int out_size, void* d_ws, size_t ws_size,
                              hipStream_t stream) {
    const float* x      = (const float*)d_in[0];
    const float* qkv_w  = (const float*)d_in[1];
    const float* qkv_b  = (const float*)d_in[2];
    const float* out_w  = (const float*)d_in[3];
    const float* out_b  = (const float*)d_in[4];
    const float* ln1_g  = (const float*)d_in[5];
    const float* ln1_b  = (const float*)d_in[6];
    const float* ln2_g  = (const float*)d_in[7];
    const float* ln2_b  = (const float*)d_in[8];
    const float* ffn1_w = (const float*)d_in[9];
    const float* ffn1_b = (const float*)d_in[10];
    const float* ffn2_w = (const float*)d_in[11];
    const float* ffn2_b = (const float*)d_in[12];
    float* out = (float*)d_out;
    char* ws = (char*)d_ws;

    constexpr size_t SZ_XB      = 4096ull * 1024 * 2;
    constexpr size_t SZ_QKV_WT  = 3072ull * 1024 * 2;
    constexpr size_t SZ_OUT_WT  = 1024ull * 1024 * 2;
    constexpr size_t SZ_FFN1_WT = 4096ull * 1024 * 2;
    constexpr size_t SZ_FFN2_WT = 1024ull * 4096 * 2;
    constexpr size_t SZ_CS      = 2048ull * 32 * 8;
    constexpr size_t SZ_X1F     = 4096ull * 1024 * 4;
    constexpr size_t SZ_X1H     = 4096ull * 1024 * 2;
    constexpr size_t SZ_FFN2O   = 4096ull * 1024 * 4;
    constexpr size_t SZ_QH      = 32ull * 2048 * 64 * 2;   // 8 MB
    constexpr size_t SZ_REGB    = 4 * SZ_QH;
    constexpr size_t SZ_REGC    = 4096ull * 3072 * 2;

    size_t o = 0;
    auto take = [&](size_t sz) { size_t p = o; o += (sz + 255) & ~(size_t)255; return p; };
    const size_t O_XB      = take(SZ_XB);
    const size_t O_QKV_WT  = take(SZ_QKV_WT);
    const size_t O_OUT_WT  = take(SZ_OUT_WT);
    const size_t O_FFN1_WT = take(SZ_FFN1_WT);
    const size_t O_FFN2_WT = take(SZ_FFN2_WT);
    const size_t O_CS      = take(SZ_CS);
    const size_t O_X1F     = take(SZ_X1F);
    const size_t O_X1H     = take(SZ_X1H);
    const size_t O_FFN2O   = take(SZ_FFN2O);
    const size_t O_REGB    = take(SZ_REGB);
    const size_t O_REGC    = take(SZ_REGC);

    f16*    xb      = (f16*)(ws + O_XB);
    f16*    qkv_wt  = (f16*)(ws + O_QKV_WT);
    f16*    out_wt  = (f16*)(ws + O_OUT_WT);
    f16*    ffn1_wt = (f16*)(ws + O_FFN1_WT);
    f16*    ffn2_wt = (f16*)(ws + O_FFN2_WT);
    float2* cs      = (float2*)(ws + O_CS);
    float*  x1f     = (float*)(ws + O_X1F);
    f16*    x1h     = (f16*)(ws + O_X1H);
    float*  ffn2o   = (float*)(ws + O_FFN2O);
    f16*    Qb      = (f16*)(ws + O_REGB);
    f16*    Kpb     = (f16*)(ws + O_REGB + SZ_QH);
    f16*    Vpb     = (f16*)(ws + O_REGB + 2 * SZ_QH);
    f16*    attn_o  = (f16*)(ws + O_REGB + 3 * SZ_QH);
    f16*    hbuf    = (f16*)(ws + O_REGB);          // ffn1 out, after ln1
    float*  proj1   = (float*)(ws + O_REGB);        // 16MB, Q/Kp dead after attn
    f16*    qkvo    = (f16*)(ws + O_REGC);
    float*  proj0   = (float*)(ws + O_REGC);
    float*  f2p1    = (float*)(ws + O_REGC);        // proj0 dead by ffn2

    // allow 128 KiB dynamic LDS for the 8-phase GEMM (ffn1 only)
    (void)hipFuncSetAttribute((const void*)&gemm8<EPI_GELU, f16, 1>,
                              hipFuncAttributeMaxDynamicSharedMemorySize, 131072);

    cast_f16_kernel<<<4096, 256, 0, stream>>>(x, xb, 4096 * 1024 / 4);
    transpose_cast_kernel<<<dim3(96, 32), 256, 0, stream>>>(qkv_w, qkv_wt, 1024, 3072);
    transpose_cast_kernel<<<dim3(32, 32), 256, 0, stream>>>(out_w, out_wt, 1024, 1024);
    transpose_cast_kernel<<<dim3(128, 32), 256, 0, stream>>>(ffn1_w, ffn1_wt, 1024, 4096);
    transpose_cast_kernel<<<dim3(32, 128), 256, 0, stream>>>(ffn2_w, ffn2_wt, 4096, 1024);
    rope_table_kernel<<<256, 256, 0, stream>>>(cs);

    gemm_bt<EPI_NONE, f16, 1><<<32 * 24, 256, 0, stream>>>(
        xb, qkv_wt, qkv_b, qkvo, nullptr, 4096, 3072, 1024);
    rope_pack_kernel<<<1024, 256, 0, stream>>>(qkvo, cs, Qb, Kpb, Vpb);
    attn_fwd<<<2048, 256, 0, stream>>>(Qb, Kpb, Vpb, attn_o);
    gemm_bt<EPI_NONE, float, 2><<<32 * 8 * 2, 256, 0, stream>>>(
        attn_o, out_wt, out_b, proj0, proj1, 4096, 1024, 1024);
    ln_fused<true, 2><<<4096, 256, 0, stream>>>(x, proj0, proj1, ln1_g, ln1_b, x1f, x1h);
    gemm8<EPI_GELU, f16, 1><<<256, 512, 131072, stream>>>(
        x1h, ffn1_wt, ffn1_b, hbuf, nullptr, nullptr, nullptr, 4096, 4096, 1024);
    gemm_bt<EPI_NONE, float, 2><<<32 * 8 * 2, 256, 0, stream>>>(
        hbuf, ffn2_wt, ffn2_b, ffn2o, f2p1, 4096, 1024, 4096);
    ln_fused<false, 2><<<4096, 256, 0, stream>>>(x1f, ffn2o, f2p1, ln2_g, ln2_b, out, nullptr);
}